// Round 16
// baseline (119.721 us; speedup 1.0000x reference)
//
#include <hip/hip_runtime.h>
#include <hip/hip_bf16.h>
#include <stdint.h>

// Problem constants
#define Bn 4
#define Ln 1024
#define Dn 1024
#define Hn 16
#define DHn 64
#define Mn (Bn*Ln)   // 4096 tokens

typedef __attribute__((ext_vector_type(8))) short short8v;   // 8 x bf16 (4 VGPRs)
typedef __attribute__((ext_vector_type(4))) float floatx4;   // MFMA accumulator

__device__ __forceinline__ unsigned short f2b(float f){
  union { float f; unsigned u; } v; v.f = f;
  unsigned r = (v.u + 0x7FFFu + ((v.u >> 16) & 1u)) >> 16;  // RNE
  return (unsigned short)r;
}
__device__ __forceinline__ unsigned short f2b_fast(float f){
  __hip_bfloat16 h = __float2bfloat16(f);   // compiler-native cvt (RNE)
  return *reinterpret_cast<unsigned short*>(&h);
}

// global -> LDS direct copy, 16B per lane.
typedef const unsigned __attribute__((address_space(1)))* gas1_t;
typedef unsigned __attribute__((address_space(3)))* las3_t;
__device__ __forceinline__ void gload16(const void* g, void* l){
  __builtin_amdgcn_global_load_lds((gas1_t)(uintptr_t)g, (las3_t)(uintptr_t)l, 16, 0, 0);
}

// ---------------------------------------------------------------------------
// prep_k: fused {4x weight transpose+convert} + {3x fp32->bf16 stream}.
// ---------------------------------------------------------------------------
__global__ __launch_bounds__(256) void prep_k(const float* __restrict__ W0,
    const float* __restrict__ W1, const float* __restrict__ W2,
    const float* __restrict__ W3, unsigned short* __restrict__ Wt0,
    unsigned short* __restrict__ Wt1, unsigned short* __restrict__ Wt2,
    unsigned short* __restrict__ Wt3, const float* __restrict__ x0,
    const float* __restrict__ x1, const float* __restrict__ x2,
    unsigned short* __restrict__ o0, unsigned short* __restrict__ o1,
    unsigned short* __restrict__ o2)
{
  __shared__ float tile[64][65];
  if (blockIdx.x < 1024){
    const int z = blockIdx.x >> 8, rem = blockIdx.x & 255;
    const float* W; unsigned short* Wt;
    switch (z){
      case 0: W = W0; Wt = Wt0; break;
      case 1: W = W1; Wt = Wt1; break;
      case 2: W = W2; Wt = Wt2; break;
      default: W = W3; Wt = Wt3; break;
    }
    const int nb = (rem & 15) * 64, kb = (rem >> 4) * 64;
    const int tx = threadIdx.x & 63, ty = threadIdx.x >> 6;  // ty 0..3
    #pragma unroll
    for (int r = 0; r < 64; r += 4)
      tile[r + ty][tx] = W[(size_t)(kb + r + ty) * 1024 + nb + tx];
    __syncthreads();
    #pragma unroll
    for (int r = 0; r < 64; r += 4)
      Wt[(size_t)(nb + r + ty) * 1024 + kb + tx] = f2b(tile[tx][r + ty]);
  } else {
    const int i = (blockIdx.x - 1024) * 256 + threadIdx.x;   // [0, 3*2^20)
    const int sel = i >> 20, idx = i & 0xFFFFF;
    const float* x = sel == 0 ? x0 : (sel == 1 ? x1 : x2);
    unsigned short* o = sel == 0 ? o0 : (sel == 1 ? o1 : o2);
    float4 v = reinterpret_cast<const float4*>(x)[idx];
    union { unsigned short u[4]; uint2 q; } p;
    p.u[0] = f2b(v.x); p.u[1] = f2b(v.y); p.u[2] = f2b(v.z); p.u[3] = f2b(v.w);
    reinterpret_cast<uint2*>(o)[idx] = p.q;
  }
}

// ---------------------------------------------------------------------------
// 8-PHASE 256x256 GEMM (r13 schedule + r15 coalesced MODE0 epilogue).
// ---------------------------------------------------------------------------
template<int MODE>
__device__ __forceinline__ void gemm8_core(const unsigned short* __restrict__ Ab,
    const unsigned short* __restrict__ Btp, const float* __restrict__ bias,
    void* __restrict__ outp, float scale, unsigned short* lds, int nt, int mt)
{
  const int tid = threadIdx.x;                 // 0..511
  const int lane = tid & 63, wave = tid >> 6;  // 8 waves
  const int wr = wave >> 2, wc = wave & 3;     // 2 x 4
  const int lg = lane >> 4, lr = lane & 15;
  const int m0 = mt * 256, n0 = nt * 256;

  const unsigned short* gAb[2];
  const unsigned short* gBb[2];
  int ldso[2];
  #pragma unroll
  for (int i = 0; i < 2; i++){
    int c = tid + 512 * i;
    int g16 = c >> 6, lrr = c & 15, lgg = (c >> 4) & 3;
    int row = g16 * 16 + lrr;
    gAb[i] = Ab  + (size_t)(m0 + row) * 1024 + lgg * 8;
    gBb[i] = Btp + (size_t)(n0 + row) * 1024 + lgg * 8;
    ldso[i] = c * 8;
  }
  auto stageA = [&](int sg){
    unsigned short* slot = lds + (sg & 3) * 16384;
    const int kcol = (sg >> 1) * 64 + (sg & 1) * 32;
    #pragma unroll
    for (int i = 0; i < 2; i++) gload16(gAb[i] + kcol, &slot[ldso[i]]);
  };
  auto stageB = [&](int sg){
    unsigned short* slot = lds + (sg & 3) * 16384 + 8192;
    const int kcol = (sg >> 1) * 64 + (sg & 1) * 32;
    #pragma unroll
    for (int i = 0; i < 2; i++) gload16(gBb[i] + kcol, &slot[ldso[i]]);
  };

  floatx4 acc[8][4] = {};

  stageA(0); stageB(0); stageA(1); stageB(1); stageA(2); stageB(2);

  for (int t = 0; t < 16; t++){
    unsigned short* slot0 = lds + ((2 * t) & 3) * 16384;
    unsigned short* slot1 = lds + ((2 * t + 1) & 3) * 16384;
    short8v af[4], bf[4];
    // p0
    if (t < 15) asm volatile("s_waitcnt vmcnt(4)" ::: "memory");
    else        asm volatile("s_waitcnt vmcnt(0)" ::: "memory");
    __builtin_amdgcn_s_barrier();
    __builtin_amdgcn_sched_barrier(0);
    if (t < 15) stageA(2 * t + 3);
    #pragma unroll
    for (int n = 0; n < 4; n++)
      bf[n] = *reinterpret_cast<const short8v*>(&slot0[8192 + ((wc * 4 + n) * 64 + lane) * 8]);
    #pragma unroll
    for (int i2 = 0; i2 < 4; i2++)
      af[i2] = *reinterpret_cast<const short8v*>(&slot0[((wr * 8 + i2) * 64 + lane) * 8]);
    __builtin_amdgcn_s_setprio(1);
    #pragma unroll
    for (int a = 0; a < 4; a++)
      #pragma unroll
      for (int n = 0; n < 4; n++)
        acc[a][n] = __builtin_amdgcn_mfma_f32_16x16x32_bf16(af[a], bf[n], acc[a][n], 0, 0, 0);
    __builtin_amdgcn_s_setprio(0);
    // p1
    if (t < 15) stageB(2 * t + 3);
    #pragma unroll
    for (int i2 = 0; i2 < 4; i2++)
      af[i2] = *reinterpret_cast<const short8v*>(&slot0[((wr * 8 + 4 + i2) * 64 + lane) * 8]);
    __builtin_amdgcn_s_setprio(1);
    #pragma unroll
    for (int a = 0; a < 4; a++)
      #pragma unroll
      for (int n = 0; n < 4; n++)
        acc[4 + a][n] = __builtin_amdgcn_mfma_f32_16x16x32_bf16(af[a], bf[n], acc[4 + a][n], 0, 0, 0);
    __builtin_amdgcn_s_setprio(0);
    // p2
    __builtin_amdgcn_sched_barrier(0);
    __builtin_amdgcn_s_barrier();
    __builtin_amdgcn_sched_barrier(0);
    if (t < 14) stageA(2 * t + 4);
    #pragma unroll
    for (int n = 0; n < 4; n++)
      bf[n] = *reinterpret_cast<const short8v*>(&slot1[8192 + ((wc * 4 + n) * 64 + lane) * 8]);
    #pragma unroll
    for (int i2 = 0; i2 < 4; i2++)
      af[i2] = *reinterpret_cast<const short8v*>(&slot1[((wr * 8 + i2) * 64 + lane) * 8]);
    __builtin_amdgcn_s_setprio(1);
    #pragma unroll
    for (int a = 0; a < 4; a++)
      #pragma unroll
      for (int n = 0; n < 4; n++)
        acc[a][n] = __builtin_amdgcn_mfma_f32_16x16x32_bf16(af[a], bf[n], acc[a][n], 0, 0, 0);
    __builtin_amdgcn_s_setprio(0);
    // p3
    if (t < 14) stageB(2 * t + 4);
    #pragma unroll
    for (int i2 = 0; i2 < 4; i2++)
      af[i2] = *reinterpret_cast<const short8v*>(&slot1[((wr * 8 + 4 + i2) * 64 + lane) * 8]);
    __builtin_amdgcn_s_setprio(1);
    #pragma unroll
    for (int a = 0; a < 4; a++)
      #pragma unroll
      for (int n = 0; n < 4; n++)
        acc[4 + a][n] = __builtin_amdgcn_mfma_f32_16x16x32_bf16(af[a], bf[n], acc[4 + a][n], 0, 0, 0);
    __builtin_amdgcn_s_setprio(0);
    __builtin_amdgcn_sched_barrier(0);
  }

  if constexpr (MODE == 2){
    __syncthreads();
    #pragma unroll
    for (int n = 0; n < 4; n++){
      const int gn_l = wc * 64 + n * 16 + lr;
      const float bb = bias[n0 + gn_l];
      const int X = (gn_l & 7) << 3;
      #pragma unroll
      for (int a = 0; a < 8; a++){
        const int gm_l = wr * 128 + a * 16 + lg * 4;
        union { unsigned short u[4]; uint2 q; } pk;
        #pragma unroll
        for (int r = 0; r < 4; r++) pk.u[r] = f2b((acc[a][n][r] + bb) * scale);
        *reinterpret_cast<uint2*>(&lds[gn_l * 256 + (gm_l ^ X)]) = pk.q;
      }
    }
    __syncthreads();
    const int bb2 = m0 >> 10, l0 = m0 & 1023;
    const int row = tid >> 1, colb = (tid & 1) * 128;
    const int h2 = (n0 + row) >> 6, d = (n0 + row) & 63;
    unsigned short* obase = (unsigned short*)outp +
        (((size_t)(bb2 * Hn + h2)) * DHn + d) * Ln + l0 + colb;
    const int XR = (row & 7) << 3;
    #pragma unroll
    for (int g = 0; g < 16; g++){
      short8v v = *reinterpret_cast<const short8v*>(&lds[row * 256 + ((colb + g * 8) ^ XR)]);
      *reinterpret_cast<short8v*>(obase + g * 8) = v;
    }
  } else {
    // per-wave repack -> coalesced 16B stores (wave-private [16][72] region)
    unsigned short* plw = lds + wave * 1152;
    unsigned short* o = (unsigned short*)outp;
    const int gnb = n0 + wc * 64;
    const int h2 = gnb >> 6;
    float bb4[4];
    #pragma unroll
    for (int n = 0; n < 4; n++) bb4[n] = bias[gnb + n * 16 + lr];
    #pragma unroll
    for (int a = 0; a < 8; a++){
      #pragma unroll
      for (int n = 0; n < 4; n++)
        #pragma unroll
        for (int r = 0; r < 4; r++)
          plw[(lg * 4 + r) * 72 + n * 16 + lr] = f2b((acc[a][n][r] + bb4[n]) * scale);
      #pragma unroll
      for (int it = 0; it < 2; it++){
        const int row = it * 8 + (lane >> 3);     // 0..15
        const int c   = lane & 7;
        const int gm  = m0 + wr * 128 + a * 16 + row;
        const int b2 = gm >> 10, l = gm & 1023;
        short8v v = *reinterpret_cast<const short8v*>(&plw[row * 72 + c * 8]);
        *reinterpret_cast<short8v*>(o + (((size_t)(b2 * Hn + h2)) * Ln + l) * DHn + c * 8) = v;
      }
    }
  }
}

// Fused Q/K/V projections, 8-phase: 192 blocks x 512 thr.
__global__ __launch_bounds__(512, 2) void gemmqkv8_k(
    const unsigned short* __restrict__ A0, const unsigned short* __restrict__ A1,
    const unsigned short* __restrict__ A2, const unsigned short* __restrict__ W0,
    const unsigned short* __restrict__ W1, const unsigned short* __restrict__ W2,
    const float* __restrict__ b0, const float* __restrict__ b1,
    const float* __restrict__ b2, unsigned short* __restrict__ o0,
    unsigned short* __restrict__ o1, unsigned short* __restrict__ o2, float qscl)
{
  __shared__ __align__(16) unsigned short lds[65536];   // 128KB: 4 slice-slots
  const int g = blockIdx.x >> 3;               // 0..23
  const int nt = g & 3;
  const int panel = (g >> 2) * 8 + (blockIdx.x & 7);   // 0..47
  const int z = panel >> 4, mt = panel & 15;
  if (z == 0)
    gemm8_core<0>(A0, W0, b0, o0, qscl, lds, nt, mt);
  else if (z == 1)
    gemm8_core<0>(A1, W1, b1, o1, 1.f, lds, nt, mt);
  else
    gemm8_core<2>(A2, W2, b2, o2, 1.f, lds, nt, mt);
}

// ---------------------------------------------------------------------------
// O-projection GEMM (r14 counted-vmcnt slice pipeline, unchanged)
// ---------------------------------------------------------------------------
__global__ __launch_bounds__(256) void gemmo_k(const unsigned short* __restrict__ Ab,
    const unsigned short* __restrict__ W, const float* __restrict__ bias,
    float* __restrict__ out, const float* __restrict__ resid)
{
  __shared__ __align__(16) unsigned short lds[32768];   // 64KB: 4 x (A8KB + B8KB)
  const int bid = blockIdx.x;
  const int xcd = bid & 7, k = bid >> 3;       // k: 0..31
  const int mt = xcd * 4 + (k >> 3);
  const int nt = k & 7;

  const int tid = threadIdx.x;
  const int lane = tid & 63, wave = tid >> 6;
  const int wr = wave >> 1, wc = wave & 1;
  const int lg = lane >> 4, lr = lane & 15;
  const int m0 = mt * 128, n0 = nt * 128;

  const unsigned short* gA[2];
  const unsigned short* gB[2];
  int ldso[2];
  #pragma unroll
  for (int i = 0; i < 2; i++){
    int c = tid + 256 * i;
    int g16 = c >> 6, lrr = c & 15, lgg = (c >> 4) & 3;
    int row = g16 * 16 + lrr;
    gA[i] = Ab + (size_t)(m0 + row) * 1024 + lgg * 8;
    gB[i] = W  + (size_t)(n0 + row) * 1024 + lgg * 8;
    ldso[i] = c * 8;
  }
  auto issue = [&](int s){
    unsigned short* base = lds + (s & 3) * 8192;
    const int kc = s * 32;
    #pragma unroll
    for (int i = 0; i < 2; i++) gload16(gA[i] + kc, &base[ldso[i]]);
    #pragma unroll
    for (int i = 0; i < 2; i++) gload16(gB[i] + kc, &base[4096 + ldso[i]]);
  };

  floatx4 acc[4][4] = {};

  issue(0); issue(1); issue(2);

  for (int s = 0; s < 32; s++){
    unsigned short* base = lds + (s & 3) * 8192;
    if (s <= 29)      asm volatile("s_waitcnt vmcnt(8)" ::: "memory");
    else if (s == 30) asm volatile("s_waitcnt vmcnt(4)" ::: "memory");
    else              asm volatile("s_waitcnt vmcnt(0)" ::: "memory");
    __builtin_amdgcn_s_barrier();
    __builtin_amdgcn_sched_barrier(0);
    if (s <= 28) issue(s + 3);
    short8v af[4], bf[4];
    #pragma unroll
    for (int m = 0; m < 4; m++)
      af[m] = *reinterpret_cast<const short8v*>(&base[((wr * 4 + m) * 64 + lane) * 8]);
    #pragma unroll
    for (int n = 0; n < 4; n++)
      bf[n] = *reinterpret_cast<const short8v*>(&base[4096 + ((wc * 4 + n) * 64 + lane) * 8]);
    __builtin_amdgcn_s_setprio(1);
    #pragma unroll
    for (int m = 0; m < 4; m++)
      #pragma unroll
      for (int n = 0; n < 4; n++)
        acc[m][n] = __builtin_amdgcn_mfma_f32_16x16x32_bf16(af[m], bf[n], acc[m][n], 0, 0, 0);
    __builtin_amdgcn_s_setprio(0);
    __builtin_amdgcn_sched_barrier(0);
  }

  #pragma unroll
  for (int n = 0; n < 4; n++){
    const int gn = n0 + wc * 64 + n * 16 + lr;
    const float bb = bias[gn];
    #pragma unroll
    for (int m = 0; m < 4; m++){
      const int gm0 = m0 + wr * 64 + m * 16 + lg * 4;
      #pragma unroll
      for (int r = 0; r < 4; r++){
        const int gm = gm0 + r;
        out[(size_t)gm * Dn + gn] = acc[m][n][r] + bb + resid[(size_t)gm * Dn + gn];
      }
    }
  }
}

// ---------------------------------------------------------------------------
// Flash attention v8: depth-2 counted-vmcnt pipeline (3 K/V buffers), mask
// staged to LDS once (off the vmem counter), ONE raw barrier per tile.
// Per tile t: { vmcnt(4) [t landed; t+1 in flight] -> s_barrier ->
//   issue t+2 -> QK MFMA -> softmax (mask from LDS) -> P -> PV MFMA }.
// LDS 70KB -> 2 blocks/CU = exactly the grid's 512/256 residency.
// ---------------------------------------------------------------------------
__global__ __launch_bounds__(256) void attn_k(const unsigned short* __restrict__ qb,
    const unsigned short* __restrict__ kbf, const unsigned short* __restrict__ vtb,
    const int* __restrict__ kmask, unsigned short* __restrict__ ctx)
{
  const int bh = blockIdx.x;        // 0..63
  const int qt = blockIdx.y;        // 0..7
  const int b = bh >> 4, h = bh & 15;
  const int tid = threadIdx.x;
  const int w = tid >> 6, lane = tid & 63;
  const int lg = lane >> 4, lr = lane & 15;

  const unsigned short* qp = qb  + (size_t)bh * Ln * DHn;
  const unsigned short* kp = kbf + (size_t)bh * Ln * DHn;
  const unsigned short* vp = vtb + (size_t)bh * DHn * Ln;
  const int q0 = qt * 128 + w * 32;

  __shared__ __align__(16) unsigned short ldsK[3][4096];   // 3 x 8KB
  __shared__ __align__(16) unsigned short ldsV[3][4096];
  __shared__ __align__(16) unsigned short plds[4][32][72]; // per-wave P (32 q-rows)
  __shared__ __align__(16) int ldsM[1024];                 // mask row (4KB)

  // q fragments first (their vmem loads precede all staging issues)
  short8v aq[2][2];                  // [qfrag][ks]
  #pragma unroll
  for (int f = 0; f < 2; f++)
    #pragma unroll
    for (int ks = 0; ks < 2; ks++)
      aq[f][ks] = *reinterpret_cast<const short8v*>(
          qp + (size_t)(q0 + f * 16 + lr) * DHn + ks * 32 + lg * 8);

  const unsigned short* gK[2];
  const unsigned short* gV[2];
  #pragma unroll
  for (int i = 0; i < 2; i++){
    int bc = w * 2 + i;             // 0..7
    int ks = bc >> 2, j = bc & 3;
    int row = j * 16 + lr, col = ks * 32 + lg * 8;
    gK[i] = kp + (size_t)row * DHn + col;   // + t*4096 per tile
    gV[i] = vp + (size_t)row * Ln  + col;   // + t*64 per tile
  }
  auto issue = [&](int t){
    unsigned short* bK = ldsK[t % 3];
    unsigned short* bV = ldsV[t % 3];
    #pragma unroll
    for (int i = 0; i < 2; i++){
      gload16(gK[i] + (size_t)t * 4096, &bK[(w * 2 + i) * 512]);
      gload16(gV[i] + (size_t)t * 64,   &bV[(w * 2 + i) * 512]);
    }
  };

  floatx4 accO[2][4] = {};
  float lsacc[2][4] = {{0.f,0.f,0.f,0.f},{0.f,0.f,0.f,0.f}};

  // prologue: mask row -> LDS (1 gload16/thread), then tiles 0 and 1
  gload16(kmask + b * Ln + w * 256 + lane * 4, &ldsM[w * 256]);
  issue(0);
  issue(1);

  for (int t = 0; t < 16; t++){
    if (t < 15) asm volatile("s_waitcnt vmcnt(4)" ::: "memory");  // tile t landed
    else        asm volatile("s_waitcnt vmcnt(0)" ::: "memory");
    __builtin_amdgcn_s_barrier();       // raw: t+1's loads stay in flight
    __builtin_amdgcn_sched_barrier(0);
    if (t < 14) issue(t + 2);           // slot (t+2)%3 == (t-1)%3: reads done

    const unsigned short* bK = ldsK[t % 3];
    const unsigned short* bV = ldsV[t % 3];

    floatx4 s[2][4] = {};
    #pragma unroll
    for (int ks = 0; ks < 2; ks++)
      #pragma unroll
      for (int j = 0; j < 4; j++){
        short8v bk = *reinterpret_cast<const short8v*>(&bK[((ks * 4 + j) * 64 + lane) * 8]);
        s[0][j] = __builtin_amdgcn_mfma_f32_16x16x32_bf16(aq[0][ks], bk, s[0][j], 0, 0, 0);
        s[1][j] = __builtin_amdgcn_mfma_f32_16x16x32_bf16(aq[1][ks], bk, s[1][j], 0, 0, 0);
      }
    int mk[4];
    #pragma unroll
    for (int j = 0; j < 4; j++) mk[j] = ldsM[t * 64 + j * 16 + lr];
    if (__all(mk[0] > 0 && mk[1] > 0 && mk[2] > 0 && mk[3] > 0)){
      #pragma unroll
      for (int f = 0; f < 2; f++)
        #pragma unroll
        for (int j = 0; j < 4; j++)
          #pragma unroll
          for (int r = 0; r < 4; r++){
            float p = __builtin_amdgcn_exp2f(s[f][j][r]);
            lsacc[f][r] += p;
            plds[w][f * 16 + lg * 4 + r][j * 16 + lr] = f2b_fast(p);
          }
    } else {
      #pragma unroll
      for (int j = 0; j < 4; j++){
        const float madd = mk[j] > 0 ? 0.f : -1e9f;
        #pragma unroll
        for (int f = 0; f < 2; f++)
          #pragma unroll
          for (int r = 0; r < 4; r++){
            float p = __builtin_amdgcn_exp2f(s[f][j][r] + madd);
            lsacc[f][r] += p;
            plds[w][f * 16 + lg * 4 + r][j * 16 + lr] = f2b_fast(p);
          }
      }
    }
    #pragma unroll
    for (int ks = 0; ks < 2; ks++){
      short8v pa0 = *reinterpret_cast<const short8v*>(&plds[w][lr][ks * 32 + lg * 8]);
      short8v pa1 = *reinterpret_cast<const short8v*>(&plds[w][16 + lr][ks * 32 + lg * 8]);
      #pragma unroll
      for (int n = 0; n < 4; n++){
        short8v bv = *reinterpret_cast<const short8v*>(&bV[((ks * 4 + n) * 64 + lane) * 8]);
        accO[0][n] = __builtin_amdgcn_mfma_f32_16x16x32_bf16(pa0, bv, accO[0][n], 0, 0, 0);
        accO[1][n] = __builtin_amdgcn_mfma_f32_16x16x32_bf16(pa1, bv, accO[1][n], 0, 0, 0);
      }
    }
  }

  #pragma unroll
  for (int f = 0; f < 2; f++)
    #pragma unroll
    for (int r = 0; r < 4; r++){
      lsacc[f][r] += __shfl_xor(lsacc[f][r], 1, 64);
      lsacc[f][r] += __shfl_xor(lsacc[f][r], 2, 64);
      lsacc[f][r] += __shfl_xor(lsacc[f][r], 4, 64);
      lsacc[f][r] += __shfl_xor(lsacc[f][r], 8, 64);
      lsacc[f][r] = 1.f / fmaxf(lsacc[f][r], 1e-20f);
    }
  // epilogue: per-wave repack in plds[w] -> 16B coalesced ctx stores
  #pragma unroll
  for (int f = 0; f < 2; f++)
    #pragma unroll
    for (int n = 0; n < 4; n++)
      #pragma unroll
      for (int r = 0; r < 4; r++)
        plds[w][f * 16 + lg * 4 + r][n * 16 + lr] = f2b_fast(accO[f][n][r] * lsacc[f][r]);
  #pragma unroll
  for (int it = 0; it < 4; it++){
    const int row = it * 8 + (lane >> 3);   // 0..31
    const int c = lane & 7;
    const int q = q0 + row;
    short8v v = *reinterpret_cast<const short8v*>(&plds[w][row][c * 8]);
    *reinterpret_cast<short8v*>(ctx + ((size_t)(b * Ln + q)) * Dn + h * DHn + c * 8) = v;
  }
}

// ---------------------------------------------------------------------------
// LayerNorm: one block per row of x[4096][1024] fp32 -> out fp32
// ---------------------------------------------------------------------------
__global__ __launch_bounds__(256) void ln_k(const float* __restrict__ x,
    const float* __restrict__ g, const float* __restrict__ bt, float* __restrict__ out)
{
  const int row = blockIdx.x;
  const int tid = threadIdx.x;
  float4 v = *reinterpret_cast<const float4*>(x + (size_t)row * 1024 + tid * 4);
  float s  = v.x + v.y + v.z + v.w;
  float sq = v.x * v.x + v.y * v.y + v.z * v.z + v.w * v.w;
  #pragma unroll
  for (int off = 32; off >= 1; off >>= 1){
    s  += __shfl_xor(s, off, 64);
    sq += __shfl_xor(sq, off, 64);
  }
  __shared__ float psm[4], pqm[4];
  const int w = tid >> 6;
  if ((tid & 63) == 0){ psm[w] = s; pqm[w] = sq; }
  __syncthreads();
  s  = psm[0] + psm[1] + psm[2] + psm[3];
  sq = pqm[0] + pqm[1] + pqm[2] + pqm[3];
  const float mean = s * (1.f / 1024.f);
  const float var  = sq * (1.f / 1024.f) - mean * mean;
  const float inv  = rsqrtf(var + 1e-5f);
  float4 gg = *reinterpret_cast<const float4*>(g  + tid * 4);
  float4 bb = *reinterpret_cast<const float4*>(bt + tid * 4);
  float4 o;
  o.x = (v.x - mean) * inv * gg.x + bb.x;
  o.y = (v.y - mean) * inv * gg.y + bb.y;
  o.z = (v.z - mean) * inv * gg.z + bb.z;
  o.w = (v.w - mean) * inv * gg.w + bb.w;
  *reinterpret_cast<float4*>(out + (size_t)row * 1024 + tid * 4) = o;
}

// ---------------------------------------------------------------------------
extern "C" void kernel_launch(void* const* d_in, const int* in_sizes, int n_in,
                              void* d_out, int out_size, void* d_ws, size_t ws_size,
                              hipStream_t stream)
{
  const float* Qin = (const float*)d_in[0];
  const float* Kin = (const float*)d_in[1];
  const float* Vin = (const float*)d_in[2];
  const int*   Kms = (const int*)d_in[3];
  const float* WQ  = (const float*)d_in[4];
  const float* bQ  = (const float*)d_in[5];
  const float* WK  = (const float*)d_in[6];
  const float* bK  = (const float*)d_in[7];
  const float* WV  = (const float*)d_in[8];
  const float* bV  = (const float*)d_in[9];
  const float* WO  = (const float*)d_in[10];
  const float* bO  = (const float*)d_in[11];
  const float* lng = (const float*)d_in[12];
  const float* lnb = (const float*)d_in[13];

  char* ws = (char*)d_ws;
  const size_t MB = 1024u * 1024u;
  unsigned short* wqt = (unsigned short*)(ws + 0 * MB);    // 1024x1024 bf16 = 2MB
  unsigned short* wkt = (unsigned short*)(ws + 2 * MB);
  unsigned short* wvt = (unsigned short*)(ws + 4 * MB);
  unsigned short* wot = (unsigned short*)(ws + 6 * MB);
  unsigned short* qbf = (unsigned short*)(ws + 8 * MB);    // [B,H,L,DH] bf16 = 8MB
  unsigned short* kbf = (unsigned short*)(ws + 16 * MB);
  unsigned short* vtb = (unsigned short*)(ws + 24 * MB);   // [B,H,DH,L]
  unsigned short* ctx = (unsigned short*)(ws + 32 * MB);   // [B,L,D] bf16
  float*          xbf = (float*)(ws + 40 * MB);            // [M,D] fp32 = 16MB
  // bf16 copies of Q,K,V inputs -- alias regions that are dead until later:
  unsigned short* cv0 = (unsigned short*)(ws + 32 * MB);   // aliases ctx (written later by attn)
  unsigned short* cv1 = (unsigned short*)(ws + 40 * MB);   // aliases xbf[0:8MB] (written later by gemmo)
  unsigned short* cv2 = (unsigned short*)(ws + 48 * MB);   // aliases xbf[8:16MB]

  dim3 blk(256);
  prep_k<<<13312, blk, 0, stream>>>(WQ, WK, WV, WO, wqt, wkt, wvt, wot,
                                    Qin, Kin, Vin, cv0, cv1, cv2);

  const float QSCL = 0.125f * 1.44269504088896f;  // fold 1/sqrt(dh) * log2(e) into q
  gemmqkv8_k<<<192, dim3(512), 0, stream>>>(cv0, cv1, cv2, wqt, wkt, wvt,
                                            bQ, bK, bV, qbf, kbf, vtb, QSCL);

  attn_k<<<dim3(64, 8), blk, 0, stream>>>(qbf, kbf, vtb, Kms, ctx);

  gemmo_k<<<256, blk, 0, stream>>>(ctx, wot, bO, xbf, Qin);

  ln_k<<<4096, blk, 0, stream>>>(xbf, lng, lnb, (float*)d_out);
}

// Round 17
// 116.792 us; speedup vs baseline: 1.0251x; 1.0251x over previous
//
#include <hip/hip_runtime.h>
#include <hip/hip_bf16.h>
#include <stdint.h>

// Problem constants
#define Bn 4
#define Ln 1024
#define Dn 1024
#define Hn 16
#define DHn 64
#define Mn (Bn*Ln)   // 4096 tokens

typedef __attribute__((ext_vector_type(8))) short short8v;   // 8 x bf16 (4 VGPRs)
typedef __attribute__((ext_vector_type(4))) float floatx4;   // MFMA accumulator

__device__ __forceinline__ unsigned short f2b(float f){
  union { float f; unsigned u; } v; v.f = f;
  unsigned r = (v.u + 0x7FFFu + ((v.u >> 16) & 1u)) >> 16;  // RNE
  return (unsigned short)r;
}
__device__ __forceinline__ unsigned short f2b_fast(float f){
  __hip_bfloat16 h = __float2bfloat16(f);   // compiler-native cvt (RNE)
  return *reinterpret_cast<unsigned short*>(&h);
}
__device__ __forceinline__ float b2f(unsigned short u){
  union { unsigned u; float f; } v; v.u = (unsigned)u << 16; return v.f;
}

// global -> LDS direct copy, 16B per lane.
typedef const unsigned __attribute__((address_space(1)))* gas1_t;
typedef unsigned __attribute__((address_space(3)))* las3_t;
__device__ __forceinline__ void gload16(const void* g, void* l){
  __builtin_amdgcn_global_load_lds((gas1_t)(uintptr_t)g, (las3_t)(uintptr_t)l, 16, 0, 0);
}

// ---------------------------------------------------------------------------
// prep_k: fused {4x weight transpose+convert} + {3x fp32->bf16 stream}.
// ---------------------------------------------------------------------------
__global__ __launch_bounds__(256) void prep_k(const float* __restrict__ W0,
    const float* __restrict__ W1, const float* __restrict__ W2,
    const float* __restrict__ W3, unsigned short* __restrict__ Wt0,
    unsigned short* __restrict__ Wt1, unsigned short* __restrict__ Wt2,
    unsigned short* __restrict__ Wt3, const float* __restrict__ x0,
    const float* __restrict__ x1, const float* __restrict__ x2,
    unsigned short* __restrict__ o0, unsigned short* __restrict__ o1,
    unsigned short* __restrict__ o2)
{
  __shared__ float tile[64][65];
  if (blockIdx.x < 1024){
    const int z = blockIdx.x >> 8, rem = blockIdx.x & 255;
    const float* W; unsigned short* Wt;
    switch (z){
      case 0: W = W0; Wt = Wt0; break;
      case 1: W = W1; Wt = Wt1; break;
      case 2: W = W2; Wt = Wt2; break;
      default: W = W3; Wt = Wt3; break;
    }
    const int nb = (rem & 15) * 64, kb = (rem >> 4) * 64;
    const int tx = threadIdx.x & 63, ty = threadIdx.x >> 6;  // ty 0..3
    #pragma unroll
    for (int r = 0; r < 64; r += 4)
      tile[r + ty][tx] = W[(size_t)(kb + r + ty) * 1024 + nb + tx];
    __syncthreads();
    #pragma unroll
    for (int r = 0; r < 64; r += 4)
      Wt[(size_t)(nb + r + ty) * 1024 + kb + tx] = f2b(tile[tx][r + ty]);
  } else {
    const int i = (blockIdx.x - 1024) * 256 + threadIdx.x;   // [0, 3*2^20)
    const int sel = i >> 20, idx = i & 0xFFFFF;
    const float* x = sel == 0 ? x0 : (sel == 1 ? x1 : x2);
    unsigned short* o = sel == 0 ? o0 : (sel == 1 ? o1 : o2);
    float4 v = reinterpret_cast<const float4*>(x)[idx];
    union { unsigned short u[4]; uint2 q; } p;
    p.u[0] = f2b(v.x); p.u[1] = f2b(v.y); p.u[2] = f2b(v.z); p.u[3] = f2b(v.w);
    reinterpret_cast<uint2*>(o)[idx] = p.q;
  }
}

// ---------------------------------------------------------------------------
// 8-PHASE 256x256 GEMM. r16 change: RELAXED vmcnt (m201's once-per-half
// pattern). FIFO proof: at p0 a thread's outstanding = the 8 loads from the
// previous tile; p0/p1 read slice 2t whose loads are older than all 8 ->
// vmcnt(8) suffices. p2 needs slice 2t+1 (oldest 4 of <=12) -> vmcnt(8).
// Tail t=15: p0 vmcnt(4) [slice 30], p2 vmcnt(0) [slice 31].
// ---------------------------------------------------------------------------
template<int MODE>
__device__ __forceinline__ void gemm8_core(const unsigned short* __restrict__ Ab,
    const unsigned short* __restrict__ Btp, const float* __restrict__ bias,
    void* __restrict__ outp, float scale, unsigned short* lds, int nt, int mt)
{
  const int tid = threadIdx.x;                 // 0..511
  const int lane = tid & 63, wave = tid >> 6;  // 8 waves
  const int wr = wave >> 2, wc = wave & 3;     // 2 x 4
  const int lg = lane >> 4, lr = lane & 15;
  const int m0 = mt * 256, n0 = nt * 256;

  const unsigned short* gAb[2];
  const unsigned short* gBb[2];
  int ldso[2];
  #pragma unroll
  for (int i = 0; i < 2; i++){
    int c = tid + 512 * i;
    int g16 = c >> 6, lrr = c & 15, lgg = (c >> 4) & 3;
    int row = g16 * 16 + lrr;
    gAb[i] = Ab  + (size_t)(m0 + row) * 1024 + lgg * 8;
    gBb[i] = Btp + (size_t)(n0 + row) * 1024 + lgg * 8;
    ldso[i] = c * 8;
  }
  auto stageA = [&](int sg){
    unsigned short* slot = lds + (sg & 3) * 16384;
    const int kcol = (sg >> 1) * 64 + (sg & 1) * 32;
    #pragma unroll
    for (int i = 0; i < 2; i++) gload16(gAb[i] + kcol, &slot[ldso[i]]);
  };
  auto stageB = [&](int sg){
    unsigned short* slot = lds + (sg & 3) * 16384 + 8192;
    const int kcol = (sg >> 1) * 64 + (sg & 1) * 32;
    #pragma unroll
    for (int i = 0; i < 2; i++) gload16(gBb[i] + kcol, &slot[ldso[i]]);
  };

  floatx4 acc[8][4] = {};

  stageA(0); stageB(0); stageA(1); stageB(1); stageA(2); stageB(2);

  for (int t = 0; t < 16; t++){
    unsigned short* slot0 = lds + ((2 * t) & 3) * 16384;
    unsigned short* slot1 = lds + ((2 * t + 1) & 3) * 16384;
    short8v af[4], bf[4];
    // p0: publish slice 2t
    if (t < 15) asm volatile("s_waitcnt vmcnt(8)" ::: "memory");
    else        asm volatile("s_waitcnt vmcnt(4)" ::: "memory");
    __builtin_amdgcn_s_barrier();
    __builtin_amdgcn_sched_barrier(0);
    if (t < 15) stageA(2 * t + 3);
    #pragma unroll
    for (int n = 0; n < 4; n++)
      bf[n] = *reinterpret_cast<const short8v*>(&slot0[8192 + ((wc * 4 + n) * 64 + lane) * 8]);
    #pragma unroll
    for (int i2 = 0; i2 < 4; i2++)
      af[i2] = *reinterpret_cast<const short8v*>(&slot0[((wr * 8 + i2) * 64 + lane) * 8]);
    __builtin_amdgcn_s_setprio(1);
    #pragma unroll
    for (int a = 0; a < 4; a++)
      #pragma unroll
      for (int n = 0; n < 4; n++)
        acc[a][n] = __builtin_amdgcn_mfma_f32_16x16x32_bf16(af[a], bf[n], acc[a][n], 0, 0, 0);
    __builtin_amdgcn_s_setprio(0);
    // p1
    if (t < 15) stageB(2 * t + 3);
    #pragma unroll
    for (int i2 = 0; i2 < 4; i2++)
      af[i2] = *reinterpret_cast<const short8v*>(&slot0[((wr * 8 + 4 + i2) * 64 + lane) * 8]);
    __builtin_amdgcn_s_setprio(1);
    #pragma unroll
    for (int a = 0; a < 4; a++)
      #pragma unroll
      for (int n = 0; n < 4; n++)
        acc[4 + a][n] = __builtin_amdgcn_mfma_f32_16x16x32_bf16(af[a], bf[n], acc[4 + a][n], 0, 0, 0);
    __builtin_amdgcn_s_setprio(0);
    // p2: publish slice 2t+1
    __builtin_amdgcn_sched_barrier(0);
    if (t < 15) asm volatile("s_waitcnt vmcnt(8)" ::: "memory");
    else        asm volatile("s_waitcnt vmcnt(0)" ::: "memory");
    __builtin_amdgcn_s_barrier();
    __builtin_amdgcn_sched_barrier(0);
    if (t < 14) stageA(2 * t + 4);
    #pragma unroll
    for (int n = 0; n < 4; n++)
      bf[n] = *reinterpret_cast<const short8v*>(&slot1[8192 + ((wc * 4 + n) * 64 + lane) * 8]);
    #pragma unroll
    for (int i2 = 0; i2 < 4; i2++)
      af[i2] = *reinterpret_cast<const short8v*>(&slot1[((wr * 8 + i2) * 64 + lane) * 8]);
    __builtin_amdgcn_s_setprio(1);
    #pragma unroll
    for (int a = 0; a < 4; a++)
      #pragma unroll
      for (int n = 0; n < 4; n++)
        acc[a][n] = __builtin_amdgcn_mfma_f32_16x16x32_bf16(af[a], bf[n], acc[a][n], 0, 0, 0);
    __builtin_amdgcn_s_setprio(0);
    // p3
    if (t < 14) stageB(2 * t + 4);
    #pragma unroll
    for (int i2 = 0; i2 < 4; i2++)
      af[i2] = *reinterpret_cast<const short8v*>(&slot1[((wr * 8 + 4 + i2) * 64 + lane) * 8]);
    __builtin_amdgcn_s_setprio(1);
    #pragma unroll
    for (int a = 0; a < 4; a++)
      #pragma unroll
      for (int n = 0; n < 4; n++)
        acc[4 + a][n] = __builtin_amdgcn_mfma_f32_16x16x32_bf16(af[a], bf[n], acc[4 + a][n], 0, 0, 0);
    __builtin_amdgcn_s_setprio(0);
    __builtin_amdgcn_sched_barrier(0);
  }

  if constexpr (MODE == 2){
    __syncthreads();
    #pragma unroll
    for (int n = 0; n < 4; n++){
      const int gn_l = wc * 64 + n * 16 + lr;
      const float bb = bias[n0 + gn_l];
      const int X = (gn_l & 7) << 3;
      #pragma unroll
      for (int a = 0; a < 8; a++){
        const int gm_l = wr * 128 + a * 16 + lg * 4;
        union { unsigned short u[4]; uint2 q; } pk;
        #pragma unroll
        for (int r = 0; r < 4; r++) pk.u[r] = f2b((acc[a][n][r] + bb) * scale);
        *reinterpret_cast<uint2*>(&lds[gn_l * 256 + (gm_l ^ X)]) = pk.q;
      }
    }
    __syncthreads();
    const int bb2 = m0 >> 10, l0 = m0 & 1023;
    const int row = tid >> 1, colb = (tid & 1) * 128;
    const int h2 = (n0 + row) >> 6, d = (n0 + row) & 63;
    unsigned short* obase = (unsigned short*)outp +
        (((size_t)(bb2 * Hn + h2)) * DHn + d) * Ln + l0 + colb;
    const int XR = (row & 7) << 3;
    #pragma unroll
    for (int g = 0; g < 16; g++){
      short8v v = *reinterpret_cast<const short8v*>(&lds[row * 256 + ((colb + g * 8) ^ XR)]);
      *reinterpret_cast<short8v*>(obase + g * 8) = v;
    }
  } else {
    // per-wave repack -> coalesced 16B stores (wave-private [16][72] region)
    unsigned short* plw = lds + wave * 1152;
    unsigned short* o = (unsigned short*)outp;
    const int gnb = n0 + wc * 64;
    const int h2 = gnb >> 6;
    float bb4[4];
    #pragma unroll
    for (int n = 0; n < 4; n++) bb4[n] = bias[gnb + n * 16 + lr];
    #pragma unroll
    for (int a = 0; a < 8; a++){
      #pragma unroll
      for (int n = 0; n < 4; n++)
        #pragma unroll
        for (int r = 0; r < 4; r++)
          plw[(lg * 4 + r) * 72 + n * 16 + lr] = f2b((acc[a][n][r] + bb4[n]) * scale);
      #pragma unroll
      for (int it = 0; it < 2; it++){
        const int row = it * 8 + (lane >> 3);     // 0..15
        const int c   = lane & 7;
        const int gm  = m0 + wr * 128 + a * 16 + row;
        const int b2 = gm >> 10, l = gm & 1023;
        short8v v = *reinterpret_cast<const short8v*>(&plw[row * 72 + c * 8]);
        *reinterpret_cast<short8v*>(o + (((size_t)(b2 * Hn + h2)) * Ln + l) * DHn + c * 8) = v;
      }
    }
  }
}

// Fused Q/K/V projections, 8-phase: 192 blocks x 512 thr.
__global__ __launch_bounds__(512, 2) void gemmqkv8_k(
    const unsigned short* __restrict__ A0, const unsigned short* __restrict__ A1,
    const unsigned short* __restrict__ A2, const unsigned short* __restrict__ W0,
    const unsigned short* __restrict__ W1, const unsigned short* __restrict__ W2,
    const float* __restrict__ b0, const float* __restrict__ b1,
    const float* __restrict__ b2, unsigned short* __restrict__ o0,
    unsigned short* __restrict__ o1, unsigned short* __restrict__ o2, float qscl)
{
  __shared__ __align__(16) unsigned short lds[65536];   // 128KB: 4 slice-slots
  const int g = blockIdx.x >> 3;               // 0..23
  const int nt = g & 3;
  const int panel = (g >> 2) * 8 + (blockIdx.x & 7);   // 0..47
  const int z = panel >> 4, mt = panel & 15;
  if (z == 0)
    gemm8_core<0>(A0, W0, b0, o0, qscl, lds, nt, mt);
  else if (z == 1)
    gemm8_core<0>(A1, W1, b1, o1, 1.f, lds, nt, mt);
  else
    gemm8_core<2>(A2, W2, b2, o2, 1.f, lds, nt, mt);
}

// ---------------------------------------------------------------------------
// O-projection GEMM: counted-vmcnt slice pipeline; NEW: writes x as BF16 via
// per-wave LDS repack -> 16B coalesced stores (halves x HBM traffic; LN reads
// bf16). resid (Q, fp32) added before conversion.
// ---------------------------------------------------------------------------
__global__ __launch_bounds__(256) void gemmo_k(const unsigned short* __restrict__ Ab,
    const unsigned short* __restrict__ W, const float* __restrict__ bias,
    unsigned short* __restrict__ out, const float* __restrict__ resid)
{
  __shared__ __align__(16) unsigned short lds[32768];   // 64KB: 4 x (A8KB + B8KB)
  const int bid = blockIdx.x;
  const int xcd = bid & 7, k = bid >> 3;       // k: 0..31
  const int mt = xcd * 4 + (k >> 3);
  const int nt = k & 7;

  const int tid = threadIdx.x;
  const int lane = tid & 63, wave = tid >> 6;
  const int wr = wave >> 1, wc = wave & 1;
  const int lg = lane >> 4, lr = lane & 15;
  const int m0 = mt * 128, n0 = nt * 128;

  const unsigned short* gA[2];
  const unsigned short* gB[2];
  int ldso[2];
  #pragma unroll
  for (int i = 0; i < 2; i++){
    int c = tid + 256 * i;
    int g16 = c >> 6, lrr = c & 15, lgg = (c >> 4) & 3;
    int row = g16 * 16 + lrr;
    gA[i] = Ab + (size_t)(m0 + row) * 1024 + lgg * 8;
    gB[i] = W  + (size_t)(n0 + row) * 1024 + lgg * 8;
    ldso[i] = c * 8;
  }
  auto issue = [&](int s){
    unsigned short* base = lds + (s & 3) * 8192;
    const int kc = s * 32;
    #pragma unroll
    for (int i = 0; i < 2; i++) gload16(gA[i] + kc, &base[ldso[i]]);
    #pragma unroll
    for (int i = 0; i < 2; i++) gload16(gB[i] + kc, &base[4096 + ldso[i]]);
  };

  floatx4 acc[4][4] = {};

  issue(0); issue(1); issue(2);

  for (int s = 0; s < 32; s++){
    unsigned short* base = lds + (s & 3) * 8192;
    if (s <= 29)      asm volatile("s_waitcnt vmcnt(8)" ::: "memory");
    else if (s == 30) asm volatile("s_waitcnt vmcnt(4)" ::: "memory");
    else              asm volatile("s_waitcnt vmcnt(0)" ::: "memory");
    __builtin_amdgcn_s_barrier();
    __builtin_amdgcn_sched_barrier(0);
    if (s <= 28) issue(s + 3);
    short8v af[4], bf[4];
    #pragma unroll
    for (int m = 0; m < 4; m++)
      af[m] = *reinterpret_cast<const short8v*>(&base[((wr * 4 + m) * 64 + lane) * 8]);
    #pragma unroll
    for (int n = 0; n < 4; n++)
      bf[n] = *reinterpret_cast<const short8v*>(&base[4096 + ((wc * 4 + n) * 64 + lane) * 8]);
    __builtin_amdgcn_s_setprio(1);
    #pragma unroll
    for (int m = 0; m < 4; m++)
      #pragma unroll
      for (int n = 0; n < 4; n++)
        acc[m][n] = __builtin_amdgcn_mfma_f32_16x16x32_bf16(af[m], bf[n], acc[m][n], 0, 0, 0);
    __builtin_amdgcn_s_setprio(0);
    __builtin_amdgcn_sched_barrier(0);
  }

  // epilogue: acc + bias + resid -> bf16 x, per-wave repack, 16B stores.
  // wave region lds[wave*1152 .. +1152) lies in slot 0 (last read s=28,
  // >=3 barriers ago); wave-internal ordering only.
  unsigned short* plw = lds + wave * 1152;
  float bb4[4];
  #pragma unroll
  for (int n = 0; n < 4; n++) bb4[n] = bias[n0 + wc * 64 + n * 16 + lr];
  #pragma unroll
  for (int m = 0; m < 4; m++){
    #pragma unroll
    for (int n = 0; n < 4; n++){
      const int gn = n0 + wc * 64 + n * 16 + lr;
      #pragma unroll
      for (int r = 0; r < 4; r++){
        const int gm = m0 + wr * 64 + m * 16 + lg * 4 + r;
        float v = acc[m][n][r] + bb4[n] + resid[(size_t)gm * Dn + gn];
        plw[(lg * 4 + r) * 72 + n * 16 + lr] = f2b_fast(v);
      }
    }
    #pragma unroll
    for (int it = 0; it < 2; it++){
      const int row = it * 8 + (lane >> 3);   // 0..15
      const int c = lane & 7;
      const int gm = m0 + wr * 64 + m * 16 + row;
      short8v v = *reinterpret_cast<const short8v*>(&plw[row * 72 + c * 8]);
      *reinterpret_cast<short8v*>(out + (size_t)gm * Dn + n0 + wc * 64 + c * 8) = v;
    }
  }
}

// ---------------------------------------------------------------------------
// Flash attention v8 (r16, unchanged): depth-2 counted-vmcnt, mask in LDS.
// ---------------------------------------------------------------------------
__global__ __launch_bounds__(256) void attn_k(const unsigned short* __restrict__ qb,
    const unsigned short* __restrict__ kbf, const unsigned short* __restrict__ vtb,
    const int* __restrict__ kmask, unsigned short* __restrict__ ctx)
{
  const int bh = blockIdx.x;        // 0..63
  const int qt = blockIdx.y;        // 0..7
  const int b = bh >> 4, h = bh & 15;
  const int tid = threadIdx.x;
  const int w = tid >> 6, lane = tid & 63;
  const int lg = lane >> 4, lr = lane & 15;

  const unsigned short* qp = qb  + (size_t)bh * Ln * DHn;
  const unsigned short* kp = kbf + (size_t)bh * Ln * DHn;
  const unsigned short* vp = vtb + (size_t)bh * DHn * Ln;
  const int q0 = qt * 128 + w * 32;

  __shared__ __align__(16) unsigned short ldsK[3][4096];   // 3 x 8KB
  __shared__ __align__(16) unsigned short ldsV[3][4096];
  __shared__ __align__(16) unsigned short plds[4][32][72]; // per-wave P (32 q-rows)
  __shared__ __align__(16) int ldsM[1024];                 // mask row (4KB)

  short8v aq[2][2];                  // [qfrag][ks]
  #pragma unroll
  for (int f = 0; f < 2; f++)
    #pragma unroll
    for (int ks = 0; ks < 2; ks++)
      aq[f][ks] = *reinterpret_cast<const short8v*>(
          qp + (size_t)(q0 + f * 16 + lr) * DHn + ks * 32 + lg * 8);

  const unsigned short* gK[2];
  const unsigned short* gV[2];
  #pragma unroll
  for (int i = 0; i < 2; i++){
    int bc = w * 2 + i;             // 0..7
    int ks = bc >> 2, j = bc & 3;
    int row = j * 16 + lr, col = ks * 32 + lg * 8;
    gK[i] = kp + (size_t)row * DHn + col;   // + t*4096 per tile
    gV[i] = vp + (size_t)row * Ln  + col;   // + t*64 per tile
  }
  auto issue = [&](int t){
    unsigned short* bK = ldsK[t % 3];
    unsigned short* bV = ldsV[t % 3];
    #pragma unroll
    for (int i = 0; i < 2; i++){
      gload16(gK[i] + (size_t)t * 4096, &bK[(w * 2 + i) * 512]);
      gload16(gV[i] + (size_t)t * 64,   &bV[(w * 2 + i) * 512]);
    }
  };

  floatx4 accO[2][4] = {};
  float lsacc[2][4] = {{0.f,0.f,0.f,0.f},{0.f,0.f,0.f,0.f}};

  gload16(kmask + b * Ln + w * 256 + lane * 4, &ldsM[w * 256]);
  issue(0);
  issue(1);

  for (int t = 0; t < 16; t++){
    if (t < 15) asm volatile("s_waitcnt vmcnt(4)" ::: "memory");
    else        asm volatile("s_waitcnt vmcnt(0)" ::: "memory");
    __builtin_amdgcn_s_barrier();
    __builtin_amdgcn_sched_barrier(0);
    if (t < 14) issue(t + 2);

    const unsigned short* bK = ldsK[t % 3];
    const unsigned short* bV = ldsV[t % 3];

    floatx4 s[2][4] = {};
    #pragma unroll
    for (int ks = 0; ks < 2; ks++)
      #pragma unroll
      for (int j = 0; j < 4; j++){
        short8v bk = *reinterpret_cast<const short8v*>(&bK[((ks * 4 + j) * 64 + lane) * 8]);
        s[0][j] = __builtin_amdgcn_mfma_f32_16x16x32_bf16(aq[0][ks], bk, s[0][j], 0, 0, 0);
        s[1][j] = __builtin_amdgcn_mfma_f32_16x16x32_bf16(aq[1][ks], bk, s[1][j], 0, 0, 0);
      }
    int mk[4];
    #pragma unroll
    for (int j = 0; j < 4; j++) mk[j] = ldsM[t * 64 + j * 16 + lr];
    if (__all(mk[0] > 0 && mk[1] > 0 && mk[2] > 0 && mk[3] > 0)){
      #pragma unroll
      for (int f = 0; f < 2; f++)
        #pragma unroll
        for (int j = 0; j < 4; j++)
          #pragma unroll
          for (int r = 0; r < 4; r++){
            float p = __builtin_amdgcn_exp2f(s[f][j][r]);
            lsacc[f][r] += p;
            plds[w][f * 16 + lg * 4 + r][j * 16 + lr] = f2b_fast(p);
          }
    } else {
      #pragma unroll
      for (int j = 0; j < 4; j++){
        const float madd = mk[j] > 0 ? 0.f : -1e9f;
        #pragma unroll
        for (int f = 0; f < 2; f++)
          #pragma unroll
          for (int r = 0; r < 4; r++){
            float p = __builtin_amdgcn_exp2f(s[f][j][r] + madd);
            lsacc[f][r] += p;
            plds[w][f * 16 + lg * 4 + r][j * 16 + lr] = f2b_fast(p);
          }
      }
    }
    #pragma unroll
    for (int ks = 0; ks < 2; ks++){
      short8v pa0 = *reinterpret_cast<const short8v*>(&plds[w][lr][ks * 32 + lg * 8]);
      short8v pa1 = *reinterpret_cast<const short8v*>(&plds[w][16 + lr][ks * 32 + lg * 8]);
      #pragma unroll
      for (int n = 0; n < 4; n++){
        short8v bv = *reinterpret_cast<const short8v*>(&bV[((ks * 4 + n) * 64 + lane) * 8]);
        accO[0][n] = __builtin_amdgcn_mfma_f32_16x16x32_bf16(pa0, bv, accO[0][n], 0, 0, 0);
        accO[1][n] = __builtin_amdgcn_mfma_f32_16x16x32_bf16(pa1, bv, accO[1][n], 0, 0, 0);
      }
    }
  }

  #pragma unroll
  for (int f = 0; f < 2; f++)
    #pragma unroll
    for (int r = 0; r < 4; r++){
      lsacc[f][r] += __shfl_xor(lsacc[f][r], 1, 64);
      lsacc[f][r] += __shfl_xor(lsacc[f][r], 2, 64);
      lsacc[f][r] += __shfl_xor(lsacc[f][r], 4, 64);
      lsacc[f][r] += __shfl_xor(lsacc[f][r], 8, 64);
      lsacc[f][r] = 1.f / fmaxf(lsacc[f][r], 1e-20f);
    }
  #pragma unroll
  for (int f = 0; f < 2; f++)
    #pragma unroll
    for (int n = 0; n < 4; n++)
      #pragma unroll
      for (int r = 0; r < 4; r++)
        plds[w][f * 16 + lg * 4 + r][n * 16 + lr] = f2b_fast(accO[f][n][r] * lsacc[f][r]);
  #pragma unroll
  for (int it = 0; it < 4; it++){
    const int row = it * 8 + (lane >> 3);   // 0..31
    const int c = lane & 7;
    const int q = q0 + row;
    short8v v = *reinterpret_cast<const short8v*>(&plds[w][row][c * 8]);
    *reinterpret_cast<short8v*>(ctx + ((size_t)(b * Ln + q)) * Dn + h * DHn + c * 8) = v;
  }
}

// ---------------------------------------------------------------------------
// LayerNorm: one block per row of x[4096][1024] BF16 -> out fp32
// ---------------------------------------------------------------------------
__global__ __launch_bounds__(256) void ln_k(const unsigned short* __restrict__ x,
    const float* __restrict__ g, const float* __restrict__ bt, float* __restrict__ out)
{
  const int row = blockIdx.x;
  const int tid = threadIdx.x;
  uint2 u = *reinterpret_cast<const uint2*>(x + (size_t)row * 1024 + tid * 4);
  float v0 = b2f((unsigned short)(u.x & 0xFFFF));
  float v1 = b2f((unsigned short)(u.x >> 16));
  float v2 = b2f((unsigned short)(u.y & 0xFFFF));
  float v3 = b2f((unsigned short)(u.y >> 16));
  float s  = v0 + v1 + v2 + v3;
  float sq = v0 * v0 + v1 * v1 + v2 * v2 + v3 * v3;
  #pragma unroll
  for (int off = 32; off >= 1; off >>= 1){
    s  += __shfl_xor(s, off, 64);
    sq += __shfl_xor(sq, off, 64);
  }
  __shared__ float psm[4], pqm[4];
  const int w = tid >> 6;
  if ((tid & 63) == 0){ psm[w] = s; pqm[w] = sq; }
  __syncthreads();
  s  = psm[0] + psm[1] + psm[2] + psm[3];
  sq = pqm[0] + pqm[1] + pqm[2] + pqm[3];
  const float mean = s * (1.f / 1024.f);
  const float var  = sq * (1.f / 1024.f) - mean * mean;
  const float inv  = rsqrtf(var + 1e-5f);
  float4 gg = *reinterpret_cast<const float4*>(g  + tid * 4);
  float4 bb = *reinterpret_cast<const float4*>(bt + tid * 4);
  float4 o;
  o.x = (v0 - mean) * inv * gg.x + bb.x;
  o.y = (v1 - mean) * inv * gg.y + bb.y;
  o.z = (v2 - mean) * inv * gg.z + bb.z;
  o.w = (v3 - mean) * inv * gg.w + bb.w;
  *reinterpret_cast<float4*>(out + (size_t)row * 1024 + tid * 4) = o;
}

// ---------------------------------------------------------------------------
extern "C" void kernel_launch(void* const* d_in, const int* in_sizes, int n_in,
                              void* d_out, int out_size, void* d_ws, size_t ws_size,
                              hipStream_t stream)
{
  const float* Qin = (const float*)d_in[0];
  const float* Kin = (const float*)d_in[1];
  const float* Vin = (const float*)d_in[2];
  const int*   Kms = (const int*)d_in[3];
  const float* WQ  = (const float*)d_in[4];
  const float* bQ  = (const float*)d_in[5];
  const float* WK  = (const float*)d_in[6];
  const float* bK  = (const float*)d_in[7];
  const float* WV  = (const float*)d_in[8];
  const float* bV  = (const float*)d_in[9];
  const float* WO  = (const float*)d_in[10];
  const float* bO  = (const float*)d_in[11];
  const float* lng = (const float*)d_in[12];
  const float* lnb = (const float*)d_in[13];

  char* ws = (char*)d_ws;
  const size_t MB = 1024u * 1024u;
  unsigned short* wqt = (unsigned short*)(ws + 0 * MB);    // 1024x1024 bf16 = 2MB
  unsigned short* wkt = (unsigned short*)(ws + 2 * MB);
  unsigned short* wvt = (unsigned short*)(ws + 4 * MB);
  unsigned short* wot = (unsigned short*)(ws + 6 * MB);
  unsigned short* qbf = (unsigned short*)(ws + 8 * MB);    // [B,H,L,DH] bf16 = 8MB
  unsigned short* kbf = (unsigned short*)(ws + 16 * MB);
  unsigned short* vtb = (unsigned short*)(ws + 24 * MB);   // [B,H,DH,L]
  unsigned short* ctx = (unsigned short*)(ws + 32 * MB);   // [B,L,D] bf16
  unsigned short* xbh = (unsigned short*)(ws + 40 * MB);   // [M,D] bf16 x = 8MB
  // bf16 copies of Q,K,V inputs -- alias regions that are dead until later:
  unsigned short* cv0 = (unsigned short*)(ws + 32 * MB);   // aliases ctx (written later by attn)
  unsigned short* cv1 = (unsigned short*)(ws + 40 * MB);   // aliases xbh (written later by gemmo)
  unsigned short* cv2 = (unsigned short*)(ws + 48 * MB);

  dim3 blk(256);
  prep_k<<<13312, blk, 0, stream>>>(WQ, WK, WV, WO, wqt, wkt, wvt, wot,
                                    Qin, Kin, Vin, cv0, cv1, cv2);

  const float QSCL = 0.125f * 1.44269504088896f;  // fold 1/sqrt(dh) * log2(e) into q
  gemmqkv8_k<<<192, dim3(512), 0, stream>>>(cv0, cv1, cv2, wqt, wkt, wvt,
                                            bQ, bK, bV, qbf, kbf, vtb, QSCL);

  attn_k<<<dim3(64, 8), blk, 0, stream>>>(qbf, kbf, vtb, Kms, ctx);

  gemmo_k<<<256, blk, 0, stream>>>(ctx, wot, bO, xbh, Qin);

  ln_k<<<4096, blk, 0, stream>>>(xbh, lng, lnb, (float*)d_out);
}